// Round 8
// baseline (2746.907 us; speedup 1.0000x reference)
//
#include <hip/hip_runtime.h>

#define M_DIM 16384   // 8 * 2048
#define N_DIM 4096
#define K_DIM 4096
#define BK 64
#define NKT (K_DIM / BK)   // 64 K-tiles

typedef unsigned char u8;
typedef __attribute__((ext_vector_type(4))) int   i32x4;

#define AS1 __attribute__((address_space(1)))
#define AS3 __attribute__((address_space(3)))

// ---- prepass: per-row symmetric quant of A to i8, plus row scale & rowsum ----
__global__ __launch_bounds__(256)
void quant_a_kernel(const float* __restrict__ in, char* __restrict__ out,
                    float* __restrict__ srow, int* __restrict__ rsum) {
    const int row  = blockIdx.x;
    const int t    = threadIdx.x;
    const int lane = t & 63, wv = t >> 6;
    const float4* rp = (const float4*)(in + (size_t)row * K_DIM);

    float4 v[4];
#pragma unroll
    for (int j = 0; j < 4; ++j) v[j] = rp[t + 256 * j];

    float amax = 0.f;
#pragma unroll
    for (int j = 0; j < 4; ++j) {
        amax = fmaxf(amax, fmaxf(fmaxf(fabsf(v[j].x), fabsf(v[j].y)),
                                 fmaxf(fabsf(v[j].z), fabsf(v[j].w))));
    }
#pragma unroll
    for (int off = 32; off; off >>= 1) amax = fmaxf(amax, __shfl_xor(amax, off));
    __shared__ float wred[4];
    __shared__ int   sred[4];
    if (lane == 0) wred[wv] = amax;
    __syncthreads();
    amax = fmaxf(fmaxf(wred[0], wred[1]), fmaxf(wred[2], wred[3]));
    const float inv = amax > 0.f ? 127.f / amax : 0.f;

    int lsum = 0;
    unsigned* orow = (unsigned*)(out + (size_t)row * K_DIM);
#pragma unroll
    for (int j = 0; j < 4; ++j) {
        int q0 = __float2int_rn(v[j].x * inv);
        int q1 = __float2int_rn(v[j].y * inv);
        int q2 = __float2int_rn(v[j].z * inv);
        int q3 = __float2int_rn(v[j].w * inv);
        lsum += q0 + q1 + q2 + q3;
        unsigned pk = (unsigned)(q0 & 0xFF) | ((unsigned)(q1 & 0xFF) << 8) |
                      ((unsigned)(q2 & 0xFF) << 16) | ((unsigned)(q3 & 0xFF) << 24);
        orow[t + 256 * j] = pk;
    }
#pragma unroll
    for (int off = 32; off; off >>= 1) lsum += __shfl_xor(lsum, off);
    if (lane == 0) sred[wv] = lsum;
    __syncthreads();
    if (t == 0) {
        rsum[row] = sred[0] + sred[1] + sred[2] + sred[3];
        srow[row] = amax > 0.f ? amax / 127.f : 1.f;
    }
}

// ---- prepass: W int32 -> raw i8 pack (no dequant; zp corrected in epilogue) ----
__global__ __launch_bounds__(256)
void pack_w_kernel(const int* __restrict__ q, char* __restrict__ out, int n4) {
    int stride = gridDim.x * blockDim.x;
    for (int i = blockIdx.x * blockDim.x + threadIdx.x; i < n4; i += stride) {
        int4 a = ((const int4*)q)[i];
        unsigned pk = (unsigned)(a.x & 0xFF) | ((unsigned)(a.y & 0xFF) << 8) |
                      ((unsigned)(a.z & 0xFF) << 16) | ((unsigned)(a.w & 0xFF) << 24);
        ((unsigned*)out)[i] = pk;
    }
}

// ---- 256x256 i8 GEMM, role-staggered ping-pong (R5 geometry) ----
// 512 thr = 8 waves (2M x 4N), per-wave out 128x64, acc = i32x4[8][4].
// Ring-of-4 K-slots (BK=64), LDS = 128 KiB, verified swizzle.
// Wave-group A (wv<4) and B (wv>=4): one of each per SIMD. Two slots/tile:
//   slot 2u  : A = MFMA(u)          | B = read(u) + stage_B(u+3) + waits
//   slot 2u+1: A = read(u+1)+stage_A(u+4)+waits | B = MFMA(u)
// -> every slot each SIMD has one wave on the MFMA pipe and one on LDS.
// vmcnt ledger (per wave, 4 gloads/tile at its read slot, staging t+3 when
// reading t): vmcnt(8) at read-slot of t drains stage(t+1); the slot barrier
// publishes cross-wave before any foreign read (stage(t) drained by owner at
// its read-slot of t-1, barrier precedes reads of t at slots 2t-1/2t).
// Role branch is SCALAR (readfirstlane) -> s_cbranch, not exec-masked.
__global__ __launch_bounds__(512, 2)
void gemm_i8_kernel(const char* __restrict__ A, const char* __restrict__ B,
                    const float* __restrict__ srow, const int* __restrict__ rsum,
                    const float* __restrict__ wsc_p, const int* __restrict__ wzp_p,
                    const int* __restrict__ qb, const float* __restrict__ bsc_p,
                    const int* __restrict__ bzp_p, float* __restrict__ C) {
    __shared__ __align__(16) u8 lds[4 * 32768];   // 128 KiB

    // XCD-bijective swizzle + 8x4 supertiles for L2 reuse (nwg=1024, %8==0)
    const int nwg = gridDim.x;
    const int cpx = nwg >> 3;
    const int bid = blockIdx.x;
    const int swz = (bid & 7) * cpx + (bid >> 3);
    const int st = swz >> 5, wi = swz & 31;
    const int bm = (st >> 2) * 8 + (wi >> 2);
    const int bn = (st & 3) * 4 + (wi & 3);
    const int m0 = bm * 256, n0 = bn * 256;

    const int tid  = threadIdx.x;
    const int wv   = tid >> 6;
    const int lane = tid & 63;
    const int wr   = wv >> 2;     // 0..1 : wave row (128 M-rows)
    const int wcn  = wv & 3;      // 0..3 : wave col (64 N-cols)
    const int l15  = lane & 15;

    const int wvS   = __builtin_amdgcn_readfirstlane(wv);   // scalar wave id
    const bool roleA = (wvS < 4);

    // per-lane swizzled k-slot byte offset for fragment reads
    const int koff = (((lane >> 4) ^ ((lane >> 1) & 3)) << 4);

    // staging: lane writes LDS linearly; source col pre-swizzled (bytes)
    const int t8   = tid & 255;                              // id within group
    const int srt4 = t8 >> 2;                                // 0..63
    const int gcol = (((t8 & 3) ^ ((t8 >> 3) & 3)) << 4);    // pre-swizzled col
    const char* Gsrc = (roleA ? A + (size_t)(m0 + srt4) * K_DIM
                              : B + (size_t)(n0 + srt4) * K_DIM) + gcol;
    const int ldsH = roleA ? 0 : 16384;
    const int w4o  = (wv & 3) << 10;   // wave's 1KB chunk within 4KB block

    i32x4 acc[8][4] = {};
    i32x4 af[8], bfr[4];

    auto STAGE_HALF = [&](int ns, int k3) {
#pragma unroll
        for (int i = 0; i < 4; ++i)
            __builtin_amdgcn_global_load_lds(
                (const AS1 void*)(Gsrc + (size_t)i * 64 * K_DIM + k3),
                (AS3 void*)(lds + ns * 32768 + ldsH + i * 4096 + w4o), 16, 0, 0);
    };

#define READ_FRAGS(U)                                                          \
    do {                                                                       \
        const u8* Asl_ = lds + ((U) & 3) * 32768;                              \
        const u8* Bsl_ = Asl_ + 16384;                                         \
        _Pragma("unroll")                                                      \
        for (int mi = 0; mi < 8; ++mi)                                         \
            af[mi] = *(const i32x4*)(Asl_ + (wr * 128 + mi * 16 + l15) * 64 + koff); \
        _Pragma("unroll")                                                      \
        for (int ni = 0; ni < 4; ++ni)                                         \
            bfr[ni] = *(const i32x4*)(Bsl_ + (wcn * 64 + ni * 16 + l15) * 64 + koff); \
    } while (0)

#define MFMA_ALL()                                                             \
    do {                                                                       \
        __builtin_amdgcn_s_setprio(1);                                         \
        _Pragma("unroll")                                                      \
        for (int mi = 0; mi < 8; ++mi)                                         \
            _Pragma("unroll")                                                  \
            for (int ni = 0; ni < 4; ++ni)                                     \
                acc[mi][ni] = __builtin_amdgcn_mfma_i32_16x16x64_i8(           \
                    af[mi], bfr[ni], acc[mi][ni], 0, 0, 0);                    \
        __builtin_amdgcn_s_setprio(0);                                         \
    } while (0)

#define VMW(T)                                                                 \
    do {                                                                       \
        if ((T) <= NKT - 4)      asm volatile("s_waitcnt vmcnt(8)" ::: "memory"); \
        else if ((T) == NKT - 3) asm volatile("s_waitcnt vmcnt(4)" ::: "memory"); \
        else                     asm volatile("s_waitcnt vmcnt(0)" ::: "memory"); \
    } while (0)

#define BAR() do { __builtin_amdgcn_s_barrier();                               \
                   __builtin_amdgcn_sched_barrier(0); } while (0)

    // ---- prologue: each role stages its half of tiles 0,1,2 (12 loads) ----
    STAGE_HALF(0, 0);
    STAGE_HALF(1, BK);
    STAGE_HALF(2, 2 * BK);
    asm volatile("s_waitcnt vmcnt(8)" ::: "memory");   // own tile-0 half landed
    BAR();

    // ---- pre-loop slot: A reads tile 0 and stages A-half(3) ----
    if (roleA) {
        READ_FRAGS(0);
        STAGE_HALF(3, 3 * BK);
        asm volatile("s_waitcnt lgkmcnt(0)" ::: "memory");
        asm volatile("s_waitcnt vmcnt(8)" ::: "memory");   // drains tile-1 A-half
    }
    BAR();

    // ---- main loop: 2 slots per tile ----
#pragma unroll 2
    for (int u = 0; u < NKT; ++u) {
        // slot 2u : A computes tile u, B reads tile u (+ stages B-half u+3)
        if (roleA) {
            MFMA_ALL();
        } else {
            READ_FRAGS(u);
            if (u + 3 < NKT) STAGE_HALF((u + 3) & 3, (u + 3) * BK);
            asm volatile("s_waitcnt lgkmcnt(0)" ::: "memory");
            VMW(u);
        }
        BAR();

        // slot 2u+1 : B computes tile u, A reads tile u+1 (+ stages A-half u+4)
        if (roleA) {
            if (u + 1 < NKT) {
                READ_FRAGS(u + 1);
                if (u + 4 < NKT) STAGE_HALF((u + 4) & 3, (u + 4) * BK);
                asm volatile("s_waitcnt lgkmcnt(0)" ::: "memory");
                VMW(u + 1);
            }
        } else {
            MFMA_ALL();
        }
        BAR();
    }

    // ---- epilogue: dequant + zp correction + bias ----
    const float ws  = wsc_p[0];
    const float zpf = (float)wzp_p[0];
    const float bsc = bsc_p[0];
    const float bzp = (float)bzp_p[0];
    float bias_[4];
#pragma unroll
    for (int ni = 0; ni < 4; ++ni) {
        int col = n0 + wcn * 64 + ni * 16 + l15;
        bias_[ni] = ((float)qb[col] - bzp) * bsc;
    }
#pragma unroll
    for (int mi = 0; mi < 8; ++mi) {
        int rbase = m0 + wr * 128 + mi * 16 + (lane >> 4) * 4;
        float fs_[4], fc_[4];
#pragma unroll
        for (int i = 0; i < 4; ++i) {
            float sf = ws * srow[rbase + i];
            fs_[i] = sf;
            fc_[i] = -sf * zpf * (float)rsum[rbase + i];
        }
#pragma unroll
        for (int ni = 0; ni < 4; ++ni) {
            int col = n0 + wcn * 64 + ni * 16 + l15;
#pragma unroll
            for (int i = 0; i < 4; ++i)
                C[(size_t)(rbase + i) * N_DIM + col] =
                    fs_[i] * (float)acc[mi][ni][i] + fc_[i] + bias_[ni];
        }
    }
#undef READ_FRAGS
#undef MFMA_ALL
#undef VMW
#undef BAR
}

// ---- fallback (only if ws too small): correct, slow ----
__global__ void gemm_fallback_kernel(const float* __restrict__ A, const int* __restrict__ Wq,
                                     const float* __restrict__ wsc_p, const int* __restrict__ wzp_p,
                                     const int* __restrict__ qb, const float* __restrict__ bsc_p,
                                     const int* __restrict__ bzp_p, float* __restrict__ C) {
    int m = blockIdx.y;
    int n = blockIdx.x * 256 + threadIdx.x;
    float zp = (float)wzp_p[0];
    float sc = wsc_p[0];
    __shared__ float Arow[512];
    float acc = 0.f;
    for (int k0 = 0; k0 < K_DIM; k0 += 512) {
        __syncthreads();
        for (int t = threadIdx.x; t < 512; t += 256)
            Arow[t] = A[(size_t)m * K_DIM + k0 + t];
        __syncthreads();
        const int4* wp = (const int4*)(Wq + (size_t)n * K_DIM + k0);
        for (int kk = 0; kk < 512; kk += 4) {
            int4 q = wp[kk >> 2];
            acc += Arow[kk]     * ((float)q.x - zp);
            acc += Arow[kk + 1] * ((float)q.y - zp);
            acc += Arow[kk + 2] * ((float)q.z - zp);
            acc += Arow[kk + 3] * ((float)q.w - zp);
        }
    }
    acc *= sc;
    acc += ((float)qb[n] - (float)bzp_p[0]) * bsc_p[0];
    C[(size_t)m * N_DIM + n] = acc;
}

extern "C" void kernel_launch(void* const* d_in, const int* in_sizes, int n_in,
                              void* d_out, int out_size, void* d_ws, size_t ws_size,
                              hipStream_t stream) {
    (void)in_sizes; (void)n_in; (void)out_size;
    const float* input = (const float*)d_in[0];
    const int*   qw    = (const int*)d_in[1];
    const float* wsc   = (const float*)d_in[2];
    const int*   wzp   = (const int*)d_in[3];
    const int*   qb    = (const int*)d_in[4];
    const float* bsc   = (const float*)d_in[5];
    const int*   bzp   = (const int*)d_in[6];
    float* out = (float*)d_out;

    size_t offA = 0;
    size_t offW = (size_t)M_DIM * K_DIM;                 // 64 MB (i8)
    size_t offS = offW + (size_t)N_DIM * K_DIM;          // +16 MB
    size_t offR = offS + (size_t)M_DIM * sizeof(float);  // +64 KB
    size_t need = offR + (size_t)M_DIM * sizeof(int);    // ~80.1 MB

    if (ws_size >= need) {
        char*  Aq = (char*)d_ws + offA;
        char*  Wq8 = (char*)d_ws + offW;
        float* S  = (float*)((char*)d_ws + offS);
        int*   R  = (int*)((char*)d_ws + offR);
        quant_a_kernel<<<M_DIM, 256, 0, stream>>>(input, Aq, S, R);
        pack_w_kernel<<<2048, 256, 0, stream>>>(qw, Wq8, N_DIM * K_DIM / 4);
        gemm_i8_kernel<<<(M_DIM / 256) * (N_DIM / 256), 512, 0, stream>>>(
            Aq, Wq8, S, R, wsc, wzp, qb, bsc, bzp, out);
    } else {
        dim3 grid(N_DIM / 256, M_DIM);
        gemm_fallback_kernel<<<grid, 256, 0, stream>>>(input, qw, wsc, wzp, qb, bsc, bzp, out);
    }
}

// Round 9
// 379.025 us; speedup vs baseline: 7.2473x; 7.2473x over previous
//
#include <hip/hip_runtime.h>

#define M_DIM 16384   // 8 * 2048
#define N_DIM 4096
#define K_DIM 4096
#define BK 64
#define NKT (K_DIM / BK)   // 64 K-tiles

typedef unsigned char u8;
typedef __attribute__((ext_vector_type(4))) int   i32x4;

#define AS1 __attribute__((address_space(1)))
#define AS3 __attribute__((address_space(3)))

// ---- prepass: per-row symmetric quant of A to i8, plus row scale & rowsum ----
__global__ __launch_bounds__(256)
void quant_a_kernel(const float* __restrict__ in, char* __restrict__ out,
                    float* __restrict__ srow, int* __restrict__ rsum) {
    const int row  = blockIdx.x;
    const int t    = threadIdx.x;
    const int lane = t & 63, wv = t >> 6;
    const float4* rp = (const float4*)(in + (size_t)row * K_DIM);

    float4 v[4];
#pragma unroll
    for (int j = 0; j < 4; ++j) v[j] = rp[t + 256 * j];

    float amax = 0.f;
#pragma unroll
    for (int j = 0; j < 4; ++j) {
        amax = fmaxf(amax, fmaxf(fmaxf(fabsf(v[j].x), fabsf(v[j].y)),
                                 fmaxf(fabsf(v[j].z), fabsf(v[j].w))));
    }
#pragma unroll
    for (int off = 32; off; off >>= 1) amax = fmaxf(amax, __shfl_xor(amax, off));
    __shared__ float wred[4];
    __shared__ int   sred[4];
    if (lane == 0) wred[wv] = amax;
    __syncthreads();
    amax = fmaxf(fmaxf(wred[0], wred[1]), fmaxf(wred[2], wred[3]));
    const float inv = amax > 0.f ? 127.f / amax : 0.f;

    int lsum = 0;
    unsigned* orow = (unsigned*)(out + (size_t)row * K_DIM);
#pragma unroll
    for (int j = 0; j < 4; ++j) {
        int q0 = __float2int_rn(v[j].x * inv);
        int q1 = __float2int_rn(v[j].y * inv);
        int q2 = __float2int_rn(v[j].z * inv);
        int q3 = __float2int_rn(v[j].w * inv);
        lsum += q0 + q1 + q2 + q3;
        unsigned pk = (unsigned)(q0 & 0xFF) | ((unsigned)(q1 & 0xFF) << 8) |
                      ((unsigned)(q2 & 0xFF) << 16) | ((unsigned)(q3 & 0xFF) << 24);
        orow[t + 256 * j] = pk;
    }
#pragma unroll
    for (int off = 32; off; off >>= 1) lsum += __shfl_xor(lsum, off);
    if (lane == 0) sred[wv] = lsum;
    __syncthreads();
    if (t == 0) {
        rsum[row] = sred[0] + sred[1] + sred[2] + sred[3];
        srow[row] = amax > 0.f ? amax / 127.f : 1.f;
    }
}

// ---- prepass: W int32 -> raw i8 pack (no dequant; zp corrected in epilogue) ----
__global__ __launch_bounds__(256)
void pack_w_kernel(const int* __restrict__ q, char* __restrict__ out, int n4) {
    int stride = gridDim.x * blockDim.x;
    for (int i = blockIdx.x * blockDim.x + threadIdx.x; i < n4; i += stride) {
        int4 a = ((const int4*)q)[i];
        unsigned pk = (unsigned)(a.x & 0xFF) | ((unsigned)(a.y & 0xFF) << 8) |
                      ((unsigned)(a.z & 0xFF) << 16) | ((unsigned)(a.w & 0xFF) << 24);
        ((unsigned*)out)[i] = pk;
    }
}

// ---- 256x256 i8 GEMM, ring-of-4 K-slots (BK=64), ONE barrier per K-tile ----
// R5 geometry (best measured: 288us), with the read->MFMA serializer REMOVED:
// no explicit lgkmcnt(0)/sched_barrier between ds_reads and MFMAs — the
// compiler inserts fine-grained per-dependency lgkm waits (m97 finding), so
// early MFMAs overlap late reads, within-wave and across waves.
// Read order bfr[0..3] then af[0..7]: LDS returns in-order, so the first
// MFMA (af0 x bfr0..3) is ready after 5 reads.
// lgkmcnt(0) retained ONLY at tile end (correctness: reads must retire
// before stage(u+3) overwrites the ring slot after the barrier).
__global__ __launch_bounds__(512, 2)
void gemm_i8_kernel(const char* __restrict__ A, const char* __restrict__ B,
                    const float* __restrict__ srow, const int* __restrict__ rsum,
                    const float* __restrict__ wsc_p, const int* __restrict__ wzp_p,
                    const int* __restrict__ qb, const float* __restrict__ bsc_p,
                    const int* __restrict__ bzp_p, float* __restrict__ C) {
    __shared__ __align__(16) u8 lds[4 * 32768];   // 128 KiB

    // XCD-bijective swizzle + 8x4 supertiles for L2 reuse (nwg=1024, %8==0)
    const int nwg = gridDim.x;
    const int cpx = nwg >> 3;
    const int bid = blockIdx.x;
    const int swz = (bid & 7) * cpx + (bid >> 3);
    const int st = swz >> 5, wi = swz & 31;
    const int bm = (st >> 2) * 8 + (wi >> 2);
    const int bn = (st & 3) * 4 + (wi & 3);
    const int m0 = bm * 256, n0 = bn * 256;

    const int tid  = threadIdx.x;
    const int wv   = tid >> 6;
    const int lane = tid & 63;
    const int wr   = wv >> 2;     // 0..1 : wave row (128 M-rows)
    const int wcn  = wv & 3;      // 0..3 : wave col (64 N-cols)
    const int l15  = lane & 15;

    // per-lane swizzled k-slot byte offset for fragment reads
    const int koff = (((lane >> 4) ^ ((lane >> 1) & 3)) << 4);

    // staging: lane writes LDS linearly; source col pre-swizzled (bytes)
    const int srt  = tid >> 2;                               // 0..127
    const int gcol = (((tid & 3) ^ ((tid >> 3) & 3)) << 4);  // pre-swizzled col
    const char* AgT = A + (size_t)(m0 + srt) * K_DIM + gcol;
    const char* BgT = B + (size_t)(n0 + srt) * K_DIM + gcol;
    const int wvo = wv << 10;    // wave chunk: 64 lanes * 16 B

    i32x4 acc[8][4] = {};

    auto STAGE_A = [&](int ns, int k3) {
#pragma unroll
        for (int i = 0; i < 2; ++i)
            __builtin_amdgcn_global_load_lds(
                (const AS1 void*)(AgT + (size_t)i * 128 * K_DIM + k3),
                (AS3 void*)(lds + ns * 32768 + i * 8192 + wvo), 16, 0, 0);
    };
    auto STAGE_B = [&](int ns, int k3) {
#pragma unroll
        for (int i = 0; i < 2; ++i)
            __builtin_amdgcn_global_load_lds(
                (const AS1 void*)(BgT + (size_t)i * 128 * K_DIM + k3),
                (AS3 void*)(lds + ns * 32768 + 16384 + i * 8192 + wvo), 16, 0, 0);
    };

    // ---- prologue: stage K-tiles 0,1,2 into slots 0,1,2 (12 loads) ----
    STAGE_A(0, 0);      STAGE_B(0, 0);
    STAGE_A(1, BK);     STAGE_B(1, BK);
    STAGE_A(2, 2 * BK); STAGE_B(2, 2 * BK);
    asm volatile("s_waitcnt vmcnt(8)" ::: "memory");   // tile 0 landed
    __builtin_amdgcn_s_barrier();
    __builtin_amdgcn_sched_barrier(0);

#pragma unroll 2
    for (int u = 0; u < NKT; ++u) {
        const int cs = u & 3;
        const u8* Asl = lds + cs * 32768;
        const u8* Bsl = Asl + 16384;
        const bool pf = (u + 3) < NKT;
        const int ns = (u + 3) & 3;
        const int k3 = (u + 3) * BK;

        i32x4 af[8], bfr[4];

        // B fragments first (4 reads), then A (8 reads): in-order LDS returns
        // mean the first MFMA is ready after 5 reads.
#pragma unroll
        for (int ni = 0; ni < 4; ++ni) {
            int row = wcn * 64 + ni * 16 + l15;
            bfr[ni] = *(const i32x4*)(Bsl + row * 64 + koff);
        }
#pragma unroll
        for (int mi = 0; mi < 8; ++mi) {
            int row = wr * 128 + mi * 16 + l15;
            af[mi] = *(const i32x4*)(Asl + row * 64 + koff);
        }
        // issue next-tile staging (4 x global_load_lds; vmcnt-only, no lgkm)
        if (pf) { STAGE_A(ns, k3); STAGE_B(ns, k3); }

        // MFMAs: NO explicit lgkm drain — compiler inserts fine-grained
        // per-dependency waits, overlapping late reads with early MFMAs.
        __builtin_amdgcn_s_setprio(1);
#pragma unroll
        for (int mi = 0; mi < 8; ++mi)
#pragma unroll
            for (int ni = 0; ni < 4; ++ni)
                acc[mi][ni] = __builtin_amdgcn_mfma_i32_16x16x64_i8(
                    af[mi], bfr[ni], acc[mi][ni], 0, 0, 0);
        __builtin_amdgcn_s_setprio(0);

        // tile end: all reads retired (data-dep waits already force this;
        // explicit for the slot-reuse hazard), then counted vmcnt + barrier.
        asm volatile("s_waitcnt lgkmcnt(0)" ::: "memory");
        if (u < NKT - 3)       asm volatile("s_waitcnt vmcnt(8)" ::: "memory");
        else if (u == NKT - 3) asm volatile("s_waitcnt vmcnt(4)" ::: "memory");
        else if (u == NKT - 2) asm volatile("s_waitcnt vmcnt(0)" ::: "memory");
        __builtin_amdgcn_s_barrier();   // the ONE barrier per K-tile
        __builtin_amdgcn_sched_barrier(0);
    }

    // ---- epilogue: dequant + zp correction + bias ----
    const float ws  = wsc_p[0];
    const float zpf = (float)wzp_p[0];
    const float bsc = bsc_p[0];
    const float bzp = (float)bzp_p[0];
    float bias_[4];
#pragma unroll
    for (int ni = 0; ni < 4; ++ni) {
        int col = n0 + wcn * 64 + ni * 16 + l15;
        bias_[ni] = ((float)qb[col] - bzp) * bsc;
    }
#pragma unroll
    for (int mi = 0; mi < 8; ++mi) {
        int rbase = m0 + wr * 128 + mi * 16 + (lane >> 4) * 4;
        float fs_[4], fc_[4];
#pragma unroll
        for (int i = 0; i < 4; ++i) {
            float sf = ws * srow[rbase + i];
            fs_[i] = sf;
            fc_[i] = -sf * zpf * (float)rsum[rbase + i];
        }
#pragma unroll
        for (int ni = 0; ni < 4; ++ni) {
            int col = n0 + wcn * 64 + ni * 16 + l15;
#pragma unroll
            for (int i = 0; i < 4; ++i)
                C[(size_t)(rbase + i) * N_DIM + col] =
                    fs_[i] * (float)acc[mi][ni][i] + fc_[i] + bias_[ni];
        }
    }
}

// ---- fallback (only if ws too small): correct, slow ----
__global__ void gemm_fallback_kernel(const float* __restrict__ A, const int* __restrict__ Wq,
                                     const float* __restrict__ wsc_p, const int* __restrict__ wzp_p,
                                     const int* __restrict__ qb, const float* __restrict__ bsc_p,
                                     const int* __restrict__ bzp_p, float* __restrict__ C) {
    int m = blockIdx.y;
    int n = blockIdx.x * 256 + threadIdx.x;
    float zp = (float)wzp_p[0];
    float sc = wsc_p[0];
    __shared__ float Arow[512];
    float acc = 0.f;
    for (int k0 = 0; k0 < K_DIM; k0 += 512) {
        __syncthreads();
        for (int t = threadIdx.x; t < 512; t += 256)
            Arow[t] = A[(size_t)m * K_DIM + k0 + t];
        __syncthreads();
        const int4* wp = (const int4*)(Wq + (size_t)n * K_DIM + k0);
        for (int kk = 0; kk < 512; kk += 4) {
            int4 q = wp[kk >> 2];
            acc += Arow[kk]     * ((float)q.x - zp);
            acc += Arow[kk + 1] * ((float)q.y - zp);
            acc += Arow[kk + 2] * ((float)q.z - zp);
            acc += Arow[kk + 3] * ((float)q.w - zp);
        }
    }
    acc *= sc;
    acc += ((float)qb[n] - (float)bzp_p[0]) * bsc_p[0];
    C[(size_t)m * N_DIM + n] = acc;
}

extern "C" void kernel_launch(void* const* d_in, const int* in_sizes, int n_in,
                              void* d_out, int out_size, void* d_ws, size_t ws_size,
                              hipStream_t stream) {
    (void)in_sizes; (void)n_in; (void)out_size;
    const float* input = (const float*)d_in[0];
    const int*   qw    = (const int*)d_in[1];
    const float* wsc   = (const float*)d_in[2];
    const int*   wzp   = (const int*)d_in[3];
    const int*   qb    = (const int*)d_in[4];
    const float* bsc   = (const float*)d_in[5];
    const int*   bzp   = (const int*)d_in[6];
    float* out = (float*)d_out;

    size_t offA = 0;
    size_t offW = (size_t)M_DIM * K_DIM;                 // 64 MB (i8)
    size_t offS = offW + (size_t)N_DIM * K_DIM;          // +16 MB
    size_t offR = offS + (size_t)M_DIM * sizeof(float);  // +64 KB
    size_t need = offR + (size_t)M_DIM * sizeof(int);    // ~80.1 MB

    if (ws_size >= need) {
        char*  Aq = (char*)d_ws + offA;
        char*  Wq8 = (char*)d_ws + offW;
        float* S  = (float*)((char*)d_ws + offS);
        int*   R  = (int*)((char*)d_ws + offR);
        quant_a_kernel<<<M_DIM, 256, 0, stream>>>(input, Aq, S, R);
        pack_w_kernel<<<2048, 256, 0, stream>>>(qw, Wq8, N_DIM * K_DIM / 4);
        gemm_i8_kernel<<<(M_DIM / 256) * (N_DIM / 256), 512, 0, stream>>>(
            Aq, Wq8, S, R, wsc, wzp, qb, bsc, bzp, out);
    } else {
        dim3 grid(N_DIM / 256, M_DIM);
        gemm_fallback_kernel<<<grid, 256, 0, stream>>>(input, qw, wsc, wzp, qb, bsc, bzp, out);
    }
}